// Round 9
// baseline (347.731 us; speedup 1.0000x reference)
//
#include <hip/hip_runtime.h>

#define HID 10
#define STEPS 512

// DPP ROW_NEWBCAST (gfx90a+/CDNA): broadcast lane F of each 16-lane row to the row.
// Pure VALU (no LDS pipe, no lgkmcnt). Verified correct on gfx950 in round 8.
template<int F>
static __device__ __forceinline__ float rowbc(float v) {
    int s = __float_as_int(v);
    return __int_as_float(__builtin_amdgcn_update_dpp(s, s, 0x150 | F, 0xF, 0xF, false));
}

// Lane-parallel fused GRU decoder: 1 feature/lane, 4 batches/wave, 2048 waves (2/SIMD).
// Fused recurrence (x-path folded into gate weights, round-2 derivation):
//   r,z from (Wgi+Whh); ni from Wgi; nh from Whh; o = l1(h).
// Per wave-step: 50 scalar v_fmac (bias-init accumulators) + 10 DPP row-broadcasts
//   + 6 transcendentals + ~15 glue + 1 masked dword store. No LDS, no inline asm.
__global__ __launch_bounds__(64, 2) void gru_decoder_kernel(
    const float* __restrict__ hidden, const float* __restrict__ w_ih,
    const float* __restrict__ w_hh, const float* __restrict__ b_ih,
    const float* __restrict__ b_hh, const float* __restrict__ l1_w,
    const float* __restrict__ l1_b, const float* __restrict__ l2_w,
    const float* __restrict__ l2_b, float* __restrict__ out)
{
    __shared__ float sWx[640];   // l2_w @ l1_w (64x10)
    __shared__ float sbx[64];    // l2_w @ l1_b + l2_b
    __shared__ float sWgi[300];  // w_ih @ Wx (30x10)
    __shared__ float sbgi[30];   // b_ih + w_ih @ bx
    __shared__ float sWhh[300];  // w_hh copy (t=0 peel)

    const int lane = threadIdx.x;
    const int f    = lane & 15;
    const int b    = blockIdx.x * 4 + (lane >> 4);
    const bool ok  = (f < HID);
    const int fi   = ok ? f : 0;

    // ---- preamble: fused weights (fp32, cooperative) ----
    for (int e = lane; e < 640; e += 64) {
        int i = e / 10, j = e - i * 10;
        float acc = 0.f;
        #pragma unroll
        for (int k = 0; k < 10; ++k) acc += l2_w[i * 10 + k] * l1_w[k * 10 + j];
        sWx[e] = acc;
    }
    {
        float acc = l2_b[lane];
        #pragma unroll
        for (int k = 0; k < 10; ++k) acc += l2_w[lane * 10 + k] * l1_b[k];
        sbx[lane] = acc;
    }
    for (int e = lane; e < 300; e += 64) sWhh[e] = w_hh[e];
    __syncthreads();
    for (int e = lane; e < 300; e += 64) {
        int m = e / 10, j = e - m * 10;
        float acc = 0.f;
        for (int k = 0; k < 64; ++k) acc += w_ih[m * 64 + k] * sWx[k * 10 + j];
        sWgi[e] = acc;
    }
    if (lane < 30) {
        float acc = b_ih[lane];
        for (int k = 0; k < 64; ++k) acc += w_ih[lane * 64 + k] * sbx[k];
        sbgi[lane] = acc;
    }
    __syncthreads();

    const float LOG2E = 1.4426950408889634f;
    const float S2    = 2.f * LOG2E;

    // ---- per-lane scalar weights (feature fi; f>=10 zeroed), prefolded scales ----
    float wr[10], wz[10], wni[10], wnh[10], wo[10];
    #pragma unroll
    for (int k = 0; k < 10; ++k) {
        if (ok) {
            wr[k]  = -(sWgi[fi * 10 + k] + sWhh[fi * 10 + k]) * LOG2E;
            wz[k]  = -(sWgi[(10 + fi) * 10 + k] + sWhh[(10 + fi) * 10 + k]) * LOG2E;
            wni[k] = sWgi[(20 + fi) * 10 + k] * S2;
            wnh[k] = sWhh[(20 + fi) * 10 + k] * S2;
            wo[k]  = l1_w[fi * 10 + k];
        } else {
            wr[k] = 0.f; wz[k] = 0.f; wni[k] = 0.f; wnh[k] = 0.f; wo[k] = 0.f;
        }
    }
    const float br  = ok ? -(sbgi[fi] + b_hh[fi]) * LOG2E : 0.f;
    const float bz  = ok ? -(sbgi[10 + fi] + b_hh[10 + fi]) * LOG2E : 0.f;
    const float bni = ok ? sbgi[20 + fi] * S2 : 0.f;
    const float bnh = ok ? b_hh[20 + fi] * S2 : 0.f;
    const float bo  = ok ? l1_b[fi] : 0.f;
    const float br0  = ok ? -(b_ih[fi] + b_hh[fi]) * LOG2E : 0.f;
    const float bz0  = ok ? -(b_ih[10 + fi] + b_hh[10 + fi]) * LOG2E : 0.f;
    const float bni0 = ok ? b_ih[20 + fi] * S2 : 0.f;

    // ---- initial h (one feature per lane; f>=10 stays exactly 0) ----
    float h = ok ? hidden[(size_t)b * HID + f] : 0.f;

    float ha[10];
    #define GATHER()                                                   \
        ha[0] = rowbc<0>(h); ha[1] = rowbc<1>(h); ha[2] = rowbc<2>(h); \
        ha[3] = rowbc<3>(h); ha[4] = rowbc<4>(h); ha[5] = rowbc<5>(h); \
        ha[6] = rowbc<6>(h); ha[7] = rowbc<7>(h); ha[8] = rowbc<8>(h); \
        ha[9] = rowbc<9>(h);

    GATHER();

    float* pb = out + (size_t)b * (STEPS * HID) + (size_t)(STEPS - 1) * HID + f;

    // ---- t = 0 peeled: gi = b_ih only (x_0 = 0); raw w_hh dots from LDS ----
    {
        float pr = 0.f, pz = 0.f, ph = 0.f;
        #pragma unroll
        for (int k = 0; k < 10; ++k) {
            pr += sWhh[fi * 10 + k] * ha[k];
            pz += sWhh[(10 + fi) * 10 + k] * ha[k];
            ph += sWhh[(20 + fi) * 10 + k] * ha[k];
        }
        float vr = br0 - pr * LOG2E;
        float vz = bz0 - pz * LOG2E;
        float r = __builtin_amdgcn_rcpf(1.f + __builtin_amdgcn_exp2f(vr));
        float z = __builtin_amdgcn_rcpf(1.f + __builtin_amdgcn_exp2f(vz));
        float y = bni0 + r * (ph * S2 + bnh);
        float n = 1.f - 2.f * __builtin_amdgcn_rcpf(1.f + __builtin_amdgcn_exp2f(y));
        h = ok ? (n + z * (h - n)) : 0.f;
        GATHER();
        float o = bo;
        #pragma unroll
        for (int k = 0; k < 10; ++k) o += wo[k] * ha[k];
        if (ok) pb[0] = o;
        pb -= HID;
    }

    // one step: 4 gate dots (scalar fmac, bias-init) -> update -> DPP -> o-dot -> store
    auto STEP = [&]() {
        float ar = br, az = bz, ai = bni, ah = bnh;
        #pragma unroll
        for (int k = 0; k < 10; ++k) {
            ar += wr[k] * ha[k];
            az += wz[k] * ha[k];
            ai += wni[k] * ha[k];
            ah += wnh[k] * ha[k];
        }
        float r = __builtin_amdgcn_rcpf(1.f + __builtin_amdgcn_exp2f(ar));
        float z = __builtin_amdgcn_rcpf(1.f + __builtin_amdgcn_exp2f(az));
        float y = ai + r * ah;
        float n = 1.f - 2.f * __builtin_amdgcn_rcpf(1.f + __builtin_amdgcn_exp2f(y));
        h = n + z * (h - n);          // f>=10: zero weights/biases keep h == 0
        GATHER();
        float o = bo;
        #pragma unroll
        for (int k = 0; k < 10; ++k) o += wo[k] * ha[k];
        if (ok) pb[0] = o;
        pb -= HID;
    };

    // ---- t = 1 .. 510 as 255 unrolled pairs (store regs alternate), then tail ----
    #pragma unroll 1
    for (int tp = 0; tp < 255; ++tp) {
        STEP();
        STEP();
    }
    STEP();
}

extern "C" void kernel_launch(void* const* d_in, const int* in_sizes, int n_in,
                              void* d_out, int out_size, void* d_ws, size_t ws_size,
                              hipStream_t stream) {
    (void)in_sizes; (void)n_in; (void)d_ws; (void)ws_size; (void)out_size;
    dim3 grid(2048), block(64);   // 4 batches/wave, 2048 waves -> 2 waves per SIMD
    gru_decoder_kernel<<<grid, block, 0, stream>>>(
        (const float*)d_in[0], (const float*)d_in[1], (const float*)d_in[2],
        (const float*)d_in[3], (const float*)d_in[4], (const float*)d_in[5],
        (const float*)d_in[6], (const float*)d_in[7], (const float*)d_in[8],
        (float*)d_out);
}